// Round 4
// baseline (1594.294 us; speedup 1.0000x reference)
//
#include <hip/hip_runtime.h>

typedef unsigned short ushort_t;
typedef unsigned int uint_t;
typedef _Float16 f16;
typedef __attribute__((ext_vector_type(8))) _Float16 f16x8;
typedef __attribute__((ext_vector_type(8))) unsigned short u16x8;
typedef __attribute__((ext_vector_type(4))) float f32x4;
typedef __attribute__((ext_vector_type(4))) int i32x4;

#define IMG_S 264
#define IMG_H 262
#define PLANE (IMG_H * IMG_S)   // 69168 elements per padded plane
#define NPLANES 61              // 30 x-planes, 30 ups-planes, 1 zero plane
#define KTOT 1472               // 1470 padded to 46*32
#define KREAL 1470
#define NHID 2048
#define NPIX 65536
#define BM 128
#define BN 128
#define BK 32
#define KSTEPS (KTOT / BK)      // 46
#define SA 8.0f                 // A pre-scale (avoid fp16 denorm lo)
#define SB 512.0f               // W1 pre-scale
#define INV_S (1.0f / (SA * SB))  // exact power of two

__device__ __forceinline__ uint_t f16pair(float f) {
    // pack fp16(f) | fp16(f - fp16(f)) << 16  (hi in low bits)
    f16 h = (f16)f;
    f16 l = (f16)(f - (float)h);
    union { f16 a; ushort_t b; } uh, ul;
    uh.a = h; ul.a = l;
    return (uint_t)uh.b | ((uint_t)ul.b << 16);
}

// ---------------------------------------------------------------- pad images
// img2[plane][i][j] = packed (hi,lo) fp16 pair of SA * source pixel
__global__ void pad_imgs(const float* __restrict__ x, const float* __restrict__ xu,
                         uint_t* __restrict__ img2) {
    int idx = blockIdx.x * 256 + threadIdx.x;
    if (idx >= NPLANES * PLANE) return;
    int plane = idx / PLANE;
    int e = idx - plane * PLANE;
    int i = e / IMG_S;
    int j = e - i * IMG_S;
    uint_t v = 0;
    if (plane < 60 && i >= 3 && i < 259 && j >= 3 && j < 259) {
        const float* src = (plane < 30) ? x : xu;
        int c = (plane < 30) ? plane : plane - 30;
        float f = SA * src[(size_t)c * 65536 + (size_t)(i - 3) * 256 + (j - 3)];
        v = f16pair(f);
    }
    img2[idx] = v;
}

// ------------------------------------- W1 -> W1T hi/lo (fp16, scaled, K-padded)
__global__ void w1t_kernel(const float* __restrict__ w1,
                           ushort_t* __restrict__ w1t_hi, ushort_t* __restrict__ w1t_lo) {
    __shared__ float tile[32][33];
    const int bk  = blockIdx.x % 46;   // K tile (46*32 = 1472)
    const int bnh = blockIdx.x / 46;   // hidden tile (64*32 = 2048)
    const int t = threadIdx.x;
    const int r = t >> 5, c = t & 31;
#pragma unroll
    for (int s = 0; s < 4; ++s) {
        int kk = bk * 32 + s * 8 + r;
        int nh = bnh * 32 + c;
        tile[s * 8 + r][c] = (kk < KREAL) ? SB * w1[(size_t)kk * NHID + nh] : 0.0f;
    }
    __syncthreads();
#pragma unroll
    for (int s = 0; s < 4; ++s) {
        int nh = bnh * 32 + s * 8 + r;
        int kk = bk * 32 + c;
        float v = tile[c][s * 8 + r];
        uint_t p = f16pair(v);
        w1t_hi[(size_t)nh * KTOT + kk] = (ushort_t)(p & 0xffffu);
        w1t_lo[(size_t)nh * KTOT + kk] = (ushort_t)(p >> 16);
    }
}

// ------------------------------------------------------------- fused GEMM
// split-fp16 (hi+lo) GEMM1: 3 MFMA products per fragment pair -> fp32-class
// precision. grid = 512 row-blocks * 16 col-blocks; 256 threads (2x2 waves).
__global__ __launch_bounds__(256, 2)
void fused_gemm(const uint_t* __restrict__ img2,
                const ushort_t* __restrict__ w1t_hi,
                const ushort_t* __restrict__ w1t_lo,
                const float* __restrict__ b1,
                const float* __restrict__ w2,
                float* __restrict__ accum) {
    __shared__ ushort_t Ah[BM * BK];   // 8 KB each
    __shared__ ushort_t Al[BM * BK];
    __shared__ ushort_t Bh[BN * BK];
    __shared__ ushort_t Bl[BN * BK];
    __shared__ int boff[KTOT];         // 5888 B  (total LDS 38656 B)

    const int tid  = threadIdx.x;
    const int bid  = blockIdx.x;
    const int brow = bid >> 4;
    const int bcol = bid & 15;
    const int lane = tid & 63;
    const int wid  = tid >> 6;
    const int wm = wid >> 1;
    const int wn = wid & 1;

    // per-feature source offset table
    for (int f = tid; f < KTOT; f += 256) {
        int off;
        if (f < 720) {                    // causal from x: c=f/24, p=f%24
            int c = f / 24, p = f - c * 24;
            off = c * PLANE + (p / 7) * IMG_S + (p % 7);
        } else if (f < KREAL) {           // ups slice [720:): c=f/49, p=f%49
            int c = f / 49, p = f - c * 49;
            off = (30 + c) * PLANE + (p / 7) * IMG_S + (p % 7);
        } else {
            off = 60 * PLANE;             // zero plane (K padding)
        }
        boff[f] = off;
    }

    // staging geometry: thread t -> row t>>1, k-half (t&1)*16, two 8-groups
    const int row = tid >> 1;
    const int kh  = (tid & 1) * 16;
    const int pix0 = brow * BM;
    const int hwoff = (pix0 >> 8) * IMG_S + (pix0 & 255) + row;
    int waddr[2];
#pragma unroll
    for (int s = 0; s < 2; ++s)
        waddr[s] = (row * (BK * 2) + (kh + s * 8) * 2) ^ ((row & 7) << 4);
    const size_t brow_off = (size_t)(bcol * BN + row) * KTOT + kh;

    f32x4 zero = {0.f, 0.f, 0.f, 0.f};
    f32x4 acc[4][4];
#pragma unroll
    for (int mi = 0; mi < 4; ++mi)
#pragma unroll
        for (int ni = 0; ni < 4; ++ni) acc[mi][ni] = zero;

    for (int kt = 0; kt < KSTEPS; ++kt) {
        __syncthreads();
        // ---- stage B hi/lo (k-contiguous 16B vectors)
        const size_t bsrc = brow_off + kt * BK;
#pragma unroll
        for (int s = 0; s < 2; ++s) {
            u16x8 vh = *reinterpret_cast<const u16x8*>(w1t_hi + bsrc + s * 8);
            u16x8 vl = *reinterpret_cast<const u16x8*>(w1t_lo + bsrc + s * 8);
            *reinterpret_cast<u16x8*>((char*)Bh + waddr[s]) = vh;
            *reinterpret_cast<u16x8*>((char*)Bl + waddr[s]) = vl;
        }
        // ---- stage A: gather packed (hi,lo) dwords, de-interleave
        const int f0 = kt * BK + kh;
#pragma unroll
        for (int s = 0; s < 2; ++s) {
            i32x4 o0 = *reinterpret_cast<const i32x4*>(&boff[f0 + s * 8]);
            i32x4 o1 = *reinterpret_cast<const i32x4*>(&boff[f0 + s * 8 + 4]);
            uint_t w[8];
            w[0] = img2[o0.x + hwoff]; w[1] = img2[o0.y + hwoff];
            w[2] = img2[o0.z + hwoff]; w[3] = img2[o0.w + hwoff];
            w[4] = img2[o1.x + hwoff]; w[5] = img2[o1.y + hwoff];
            w[6] = img2[o1.z + hwoff]; w[7] = img2[o1.w + hwoff];
            u16x8 hi, lo;
#pragma unroll
            for (int i = 0; i < 8; ++i) {
                hi[i] = (ushort_t)(w[i] & 0xffffu);
                lo[i] = (ushort_t)(w[i] >> 16);
            }
            *reinterpret_cast<u16x8*>((char*)Ah + waddr[s]) = hi;
            *reinterpret_cast<u16x8*>((char*)Al + waddr[s]) = lo;
        }
        __syncthreads();
        // ---- fragments + 48 MFMA (hi*hi, hi*lo, lo*hi)
        f16x8 afh[4], afl[4], bfh[4], bfl[4];
#pragma unroll
        for (int mi = 0; mi < 4; ++mi) {
            int m = wm * 64 + mi * 16 + (lane & 15);
            int ab = (m * (BK * 2) + (lane >> 4) * 16) ^ ((m & 7) << 4);
            afh[mi] = *reinterpret_cast<const f16x8*>((char*)Ah + ab);
            afl[mi] = *reinterpret_cast<const f16x8*>((char*)Al + ab);
        }
#pragma unroll
        for (int ni = 0; ni < 4; ++ni) {
            int n = wn * 64 + ni * 16 + (lane & 15);
            int bb = (n * (BK * 2) + (lane >> 4) * 16) ^ ((n & 7) << 4);
            bfh[ni] = *reinterpret_cast<const f16x8*>((char*)Bh + bb);
            bfl[ni] = *reinterpret_cast<const f16x8*>((char*)Bl + bb);
        }
#pragma unroll
        for (int mi = 0; mi < 4; ++mi)
#pragma unroll
            for (int ni = 0; ni < 4; ++ni) {
                acc[mi][ni] = __builtin_amdgcn_mfma_f32_16x16x32_f16(
                    afh[mi], bfh[ni], acc[mi][ni], 0, 0, 0);
                acc[mi][ni] = __builtin_amdgcn_mfma_f32_16x16x32_f16(
                    afh[mi], bfl[ni], acc[mi][ni], 0, 0, 0);
                acc[mi][ni] = __builtin_amdgcn_mfma_f32_16x16x32_f16(
                    afl[mi], bfh[ni], acc[mi][ni], 0, 0, 0);
            }
    }

    // epilogue: h = relu(acc/4096 + b1); partial out = h @ W2; atomic accumulate
    float b1v[4], w2v[4][6];
#pragma unroll
    for (int ni = 0; ni < 4; ++ni) {
        int n = bcol * BN + wn * 64 + ni * 16 + (lane & 15);
        b1v[ni] = b1[n];
#pragma unroll
        for (int o = 0; o < 6; ++o) w2v[ni][o] = w2[n * 6 + o];
    }
#pragma unroll
    for (int mi = 0; mi < 4; ++mi) {
        float p[4][6];
#pragma unroll
        for (int r = 0; r < 4; ++r)
#pragma unroll
            for (int o = 0; o < 6; ++o) p[r][o] = 0.f;
#pragma unroll
        for (int ni = 0; ni < 4; ++ni) {
#pragma unroll
            for (int r = 0; r < 4; ++r) {
                float hv = fmaxf(acc[mi][ni][r] * INV_S + b1v[ni], 0.0f);
#pragma unroll
                for (int o = 0; o < 6; ++o) p[r][o] += hv * w2v[ni][o];
            }
        }
#pragma unroll
        for (int r = 0; r < 4; ++r) {
#pragma unroll
            for (int o = 0; o < 6; ++o) {
                float v = p[r][o];
                v += __shfl_xor(v, 1, 16);
                v += __shfl_xor(v, 2, 16);
                v += __shfl_xor(v, 4, 16);
                v += __shfl_xor(v, 8, 16);
                int q = r * 6 + o;
                if ((lane & 15) == (q & 15)) {
                    int orow = wm * 64 + mi * 16 + (lane >> 4) * 4 + r;
                    atomicAdd(&accum[(size_t)(pix0 + orow) * 6 + o], v);
                }
            }
        }
    }
}

// ------------------------------------------------------------- final transform
__global__ void transform_k(const float* __restrict__ accum, const float* __restrict__ b2,
                            float* __restrict__ out) {
    int n = blockIdx.x * 256 + threadIdx.x;
    if (n >= NPIX) return;
#pragma unroll
    for (int ch = 0; ch < 3; ++ch) {
        float m = accum[(size_t)n * 6 + ch * 2 + 0] + b2[ch * 2 + 0];
        float s = accum[(size_t)n * 6 + ch * 2 + 1] + b2[ch * 2 + 1];
        out[(size_t)n * 6 + ch * 2 + 0] = m * 255.0f;
        float denom = 1.0f - s + 0.1f;            // mimic reference op order
        float sc = s / denom * 100.0f;
        sc = fminf(fmaxf(sc, 1e-8f), 1000.0f);
        out[(size_t)n * 6 + ch * 2 + 1] = sc;
    }
}

// ---------------------------------------------------------------- launch
extern "C" void kernel_launch(void* const* d_in, const int* in_sizes, int n_in,
                              void* d_out, int out_size, void* d_ws, size_t ws_size,
                              hipStream_t stream) {
    const float* x  = (const float*)d_in[0];
    const float* xu = (const float*)d_in[1];
    const float* W1 = (const float*)d_in[2];
    const float* b1 = (const float*)d_in[3];
    const float* W2 = (const float*)d_in[4];
    const float* b2 = (const float*)d_in[5];
    float* out = (float*)d_out;
    char* ws = (char*)d_ws;

    // workspace layout (total ~29.1 MiB)
    const size_t OFF_W1H = 16877056;                       // img2: 61*69168*4 B
    const size_t OFF_W1L = OFF_W1H + (size_t)NHID * KTOT * 2;
    const size_t OFF_ACC = OFF_W1L + (size_t)NHID * KTOT * 2;
    uint_t* img2    = (uint_t*)ws;
    ushort_t* w1t_h = (ushort_t*)(ws + OFF_W1H);
    ushort_t* w1t_l = (ushort_t*)(ws + OFF_W1L);
    float* accum    = (float*)(ws + OFF_ACC);
    (void)ws_size; (void)in_sizes; (void)n_in; (void)out_size;

    hipMemsetAsync(accum, 0, (size_t)NPIX * 6 * sizeof(float), stream);

    int padN = NPLANES * PLANE;
    pad_imgs<<<(padN + 255) / 256, 256, 0, stream>>>(x, xu, img2);
    w1t_kernel<<<46 * 64, 256, 0, stream>>>(W1, w1t_h, w1t_l);
    fused_gemm<<<512 * 16, 256, 0, stream>>>(img2, w1t_h, w1t_l, b1, W2, accum);
    transform_k<<<NPIX / 256, 256, 0, stream>>>(accum, b2, out);
}

// Round 5
// 1501.725 us; speedup vs baseline: 1.0616x; 1.0616x over previous
//
#include <hip/hip_runtime.h>

typedef unsigned short ushort_t;
typedef unsigned int uint_t;
typedef _Float16 f16;
typedef __attribute__((ext_vector_type(8))) _Float16 f16x8;
typedef __attribute__((ext_vector_type(8))) unsigned short u16x8;
typedef __attribute__((ext_vector_type(4))) float f32x4;

#define IMG_S 264
#define IMG_H 262
#define PLANE (IMG_H * IMG_S)   // 69168 elements per padded plane
#define NPLANES 61              // 30 x-planes, 30 ups-planes, 1 zero plane
#define KTOT 1472               // 1470 padded to 46*32
#define KREAL 1470
#define NHID 2048
#define NPIX 65536
#define BM 256
#define BN 128
#define BK 32
#define KSTEPS (KTOT / BK)      // 46
#define SA 8.0f                 // A pre-scale (avoid fp16 denorm lo)
#define SB 512.0f               // W1 pre-scale
#define INV_S (1.0f / (SA * SB))  // exact power of two

__device__ __forceinline__ uint_t f16pair(float f) {
    // pack fp16(f) | fp16(f - fp16(f)) << 16  (hi in low bits)
    f16 h = (f16)f;
    f16 l = (f16)(f - (float)h);
    union { f16 a; ushort_t b; } uh, ul;
    uh.a = h; ul.a = l;
    return (uint_t)uh.b | ((uint_t)ul.b << 16);
}

// ---------------------------------------------------------------- pad images
__global__ void pad_imgs(const float* __restrict__ x, const float* __restrict__ xu,
                         uint_t* __restrict__ img2) {
    int idx = blockIdx.x * 256 + threadIdx.x;
    if (idx >= NPLANES * PLANE) return;
    int plane = idx / PLANE;
    int e = idx - plane * PLANE;
    int i = e / IMG_S;
    int j = e - i * IMG_S;
    uint_t v = 0;
    if (plane < 60 && i >= 3 && i < 259 && j >= 3 && j < 259) {
        const float* src = (plane < 30) ? x : xu;
        int c = (plane < 30) ? plane : plane - 30;
        float f = SA * src[(size_t)c * 65536 + (size_t)(i - 3) * 256 + (j - 3)];
        v = f16pair(f);
    }
    img2[idx] = v;
}

// ---------------------------------------------------------------- boff table
__global__ void boff_kernel(int* __restrict__ boff) {
    int f = blockIdx.x * 256 + threadIdx.x;
    if (f >= KTOT) return;
    int off;
    if (f < 720) {                    // causal from x: c=f/24, p=f%24
        int c = f / 24, p = f - c * 24;
        off = c * PLANE + (p / 7) * IMG_S + (p % 7);
    } else if (f < KREAL) {           // ups slice [720:): c=f/49, p=f%49
        int c = f / 49, p = f - c * 49;
        off = (30 + c) * PLANE + (p / 7) * IMG_S + (p % 7);
    } else {
        off = 60 * PLANE;             // zero plane (K padding)
    }
    boff[f] = off;
}

// ------------------------------------- W1 -> W1T hi/lo (fp16, scaled, K-padded)
__global__ void w1t_kernel(const float* __restrict__ w1,
                           ushort_t* __restrict__ w1t_hi, ushort_t* __restrict__ w1t_lo) {
    __shared__ float tile[32][33];
    const int bk  = blockIdx.x % 46;
    const int bnh = blockIdx.x / 46;
    const int t = threadIdx.x;
    const int r = t >> 5, c = t & 31;
#pragma unroll
    for (int s = 0; s < 4; ++s) {
        int kk = bk * 32 + s * 8 + r;
        int nh = bnh * 32 + c;
        tile[s * 8 + r][c] = (kk < KREAL) ? SB * w1[(size_t)kk * NHID + nh] : 0.0f;
    }
    __syncthreads();
#pragma unroll
    for (int s = 0; s < 4; ++s) {
        int nh = bnh * 32 + s * 8 + r;
        int kk = bk * 32 + c;
        float v = tile[c][s * 8 + r];
        uint_t p = f16pair(v);
        w1t_hi[(size_t)nh * KTOT + kk] = (ushort_t)(p & 0xffffu);
        w1t_lo[(size_t)nh * KTOT + kk] = (ushort_t)(p >> 16);
    }
}

// ------------------------------------------------------------- fused GEMM
// split-fp16 GEMM1, BM=256 x BN=128, BK=32; 256 threads, 2x2 waves of 128x64.
__global__ __launch_bounds__(256, 2)
void fused_gemm(const uint_t* __restrict__ img2,
                const ushort_t* __restrict__ w1t_hi,
                const ushort_t* __restrict__ w1t_lo,
                const int* __restrict__ boff,
                const float* __restrict__ b1,
                const float* __restrict__ w2,
                float* __restrict__ accum) {
    __shared__ ushort_t Ah[BM * BK];   // 16 KB
    __shared__ ushort_t Al[BM * BK];   // 16 KB
    __shared__ ushort_t Bh[BN * BK];   // 8 KB
    __shared__ ushort_t Bl[BN * BK];   // 8 KB   (total 48 KB)

    const int tid  = threadIdx.x;
    const int bid  = blockIdx.x;
    const int brow = bid >> 4;          // 256 row-blocks (h = brow)
    const int bcol = bid & 15;          // 16 col-blocks
    const int lane = tid & 63;
    const int wid  = tid >> 6;
    const int wm = wid >> 1;            // 0..1 -> 128-row half
    const int wn = wid & 1;             // 0..1 -> 64-col half

    // A staging: thread = row (pixel w = tid on image row h = brow), all 32 k
    const int hwoff = brow * IMG_S + tid;
    int aaddr[4];
#pragma unroll
    for (int s = 0; s < 4; ++s)
        aaddr[s] = (tid * (BK * 2) + s * 16) ^ ((tid & 7) << 4);
    // B staging: thread -> n-row tid>>1, k-half (tid&1)*16
    const int bn_ = tid >> 1;
    const int kh  = (tid & 1) * 16;
    int baddr[2];
#pragma unroll
    for (int s = 0; s < 2; ++s)
        baddr[s] = (bn_ * (BK * 2) + kh * 2 + s * 16) ^ ((bn_ & 7) << 4);
    const size_t bglob = (size_t)(bcol * BN + bn_) * KTOT + kh;

    f32x4 zero = {0.f, 0.f, 0.f, 0.f};
    f32x4 acc[8][4];
#pragma unroll
    for (int mi = 0; mi < 8; ++mi)
#pragma unroll
        for (int ni = 0; ni < 4; ++ni) acc[mi][ni] = zero;

    for (int kt = 0; kt < KSTEPS; ++kt) {
        __syncthreads();
        // ---- stage B hi/lo
        const size_t bsrc = bglob + kt * BK;
#pragma unroll
        for (int s = 0; s < 2; ++s) {
            u16x8 vh = *reinterpret_cast<const u16x8*>(w1t_hi + bsrc + s * 8);
            u16x8 vl = *reinterpret_cast<const u16x8*>(w1t_lo + bsrc + s * 8);
            *reinterpret_cast<u16x8*>((char*)Bh + baddr[s]) = vh;
            *reinterpret_cast<u16x8*>((char*)Bl + baddr[s]) = vl;
        }
        // ---- stage A: coalesced gather (uniform boff -> scalar loads)
        const int f0 = kt * BK;
#pragma unroll
        for (int s = 0; s < 4; ++s) {
            uint_t w[8];
#pragma unroll
            for (int i = 0; i < 8; ++i)
                w[i] = img2[boff[f0 + s * 8 + i] + hwoff];
            u16x8 hi, lo;
#pragma unroll
            for (int i = 0; i < 8; ++i) {
                hi[i] = (ushort_t)(w[i] & 0xffffu);
                lo[i] = (ushort_t)(w[i] >> 16);
            }
            *reinterpret_cast<u16x8*>((char*)Ah + aaddr[s]) = hi;
            *reinterpret_cast<u16x8*>((char*)Al + aaddr[s]) = lo;
        }
        __syncthreads();
        // ---- fragments + 96 MFMA per wave (hi*hi, hi*lo, lo*hi)
        f16x8 bfh[4], bfl[4];
#pragma unroll
        for (int ni = 0; ni < 4; ++ni) {
            int n = wn * 64 + ni * 16 + (lane & 15);
            int bb = (n * (BK * 2) + (lane >> 4) * 16) ^ ((n & 7) << 4);
            bfh[ni] = *reinterpret_cast<const f16x8*>((char*)Bh + bb);
            bfl[ni] = *reinterpret_cast<const f16x8*>((char*)Bl + bb);
        }
#pragma unroll
        for (int mi = 0; mi < 8; ++mi) {
            int m = wm * 128 + mi * 16 + (lane & 15);
            int ab = (m * (BK * 2) + (lane >> 4) * 16) ^ ((m & 7) << 4);
            f16x8 afh = *reinterpret_cast<const f16x8*>((char*)Ah + ab);
            f16x8 afl = *reinterpret_cast<const f16x8*>((char*)Al + ab);
#pragma unroll
            for (int ni = 0; ni < 4; ++ni) {
                acc[mi][ni] = __builtin_amdgcn_mfma_f32_16x16x32_f16(
                    afh, bfh[ni], acc[mi][ni], 0, 0, 0);
                acc[mi][ni] = __builtin_amdgcn_mfma_f32_16x16x32_f16(
                    afh, bfl[ni], acc[mi][ni], 0, 0, 0);
                acc[mi][ni] = __builtin_amdgcn_mfma_f32_16x16x32_f16(
                    afl, bfh[ni], acc[mi][ni], 0, 0, 0);
            }
        }
    }

    // epilogue: h = relu(acc/4096 + b1); partial out = h @ W2; atomic accumulate
    const int pix0 = brow * BM;
    float b1v[4], w2v[4][6];
#pragma unroll
    for (int ni = 0; ni < 4; ++ni) {
        int n = bcol * BN + wn * 64 + ni * 16 + (lane & 15);
        b1v[ni] = b1[n];
#pragma unroll
        for (int o = 0; o < 6; ++o) w2v[ni][o] = w2[n * 6 + o];
    }
#pragma unroll
    for (int mi = 0; mi < 8; ++mi) {
        float p[4][6];
#pragma unroll
        for (int r = 0; r < 4; ++r)
#pragma unroll
            for (int o = 0; o < 6; ++o) p[r][o] = 0.f;
#pragma unroll
        for (int ni = 0; ni < 4; ++ni) {
#pragma unroll
            for (int r = 0; r < 4; ++r) {
                float hv = fmaxf(acc[mi][ni][r] * INV_S + b1v[ni], 0.0f);
#pragma unroll
                for (int o = 0; o < 6; ++o) p[r][o] += hv * w2v[ni][o];
            }
        }
#pragma unroll
        for (int r = 0; r < 4; ++r) {
#pragma unroll
            for (int o = 0; o < 6; ++o) {
                float v = p[r][o];
                v += __shfl_xor(v, 1, 16);
                v += __shfl_xor(v, 2, 16);
                v += __shfl_xor(v, 4, 16);
                v += __shfl_xor(v, 8, 16);
                int q = r * 6 + o;
                if ((lane & 15) == (q & 15)) {
                    int orow = wm * 128 + mi * 16 + (lane >> 4) * 4 + r;
                    atomicAdd(&accum[(size_t)(pix0 + orow) * 6 + o], v);
                }
            }
        }
    }
}

// ------------------------------------------------------------- final transform
__global__ void transform_k(const float* __restrict__ accum, const float* __restrict__ b2,
                            float* __restrict__ out) {
    int n = blockIdx.x * 256 + threadIdx.x;
    if (n >= NPIX) return;
#pragma unroll
    for (int ch = 0; ch < 3; ++ch) {
        float m = accum[(size_t)n * 6 + ch * 2 + 0] + b2[ch * 2 + 0];
        float s = accum[(size_t)n * 6 + ch * 2 + 1] + b2[ch * 2 + 1];
        out[(size_t)n * 6 + ch * 2 + 0] = m * 255.0f;
        float denom = 1.0f - s + 0.1f;
        float sc = s / denom * 100.0f;
        sc = fminf(fmaxf(sc, 1e-8f), 1000.0f);
        out[(size_t)n * 6 + ch * 2 + 1] = sc;
    }
}

// ---------------------------------------------------------------- launch
extern "C" void kernel_launch(void* const* d_in, const int* in_sizes, int n_in,
                              void* d_out, int out_size, void* d_ws, size_t ws_size,
                              hipStream_t stream) {
    const float* x  = (const float*)d_in[0];
    const float* xu = (const float*)d_in[1];
    const float* W1 = (const float*)d_in[2];
    const float* b1 = (const float*)d_in[3];
    const float* W2 = (const float*)d_in[4];
    const float* b2 = (const float*)d_in[5];
    float* out = (float*)d_out;
    char* ws = (char*)d_ws;

    // workspace layout (~30.5 MiB)
    const size_t OFF_W1H  = 16877056;                       // img2: 61*69168*4 B
    const size_t OFF_W1L  = OFF_W1H + (size_t)NHID * KTOT * 2;
    const size_t OFF_ACC  = OFF_W1L + (size_t)NHID * KTOT * 2;
    const size_t OFF_BOFF = OFF_ACC + (size_t)NPIX * 6 * sizeof(float);
    uint_t* img2    = (uint_t*)ws;
    ushort_t* w1t_h = (ushort_t*)(ws + OFF_W1H);
    ushort_t* w1t_l = (ushort_t*)(ws + OFF_W1L);
    float* accum    = (float*)(ws + OFF_ACC);
    int* boff       = (int*)(ws + OFF_BOFF);
    (void)ws_size; (void)in_sizes; (void)n_in; (void)out_size;

    hipMemsetAsync(accum, 0, (size_t)NPIX * 6 * sizeof(float), stream);

    int padN = NPLANES * PLANE;
    pad_imgs<<<(padN + 255) / 256, 256, 0, stream>>>(x, xu, img2);
    boff_kernel<<<(KTOT + 255) / 256, 256, 0, stream>>>(boff);
    w1t_kernel<<<46 * 64, 256, 0, stream>>>(W1, w1t_h, w1t_l);
    fused_gemm<<<256 * 16, 256, 0, stream>>>(img2, w1t_h, w1t_l, boff, b1, W2, accum);
    transform_k<<<NPIX / 256, 256, 0, stream>>>(accum, b2, out);
}

// Round 10
// 1427.284 us; speedup vs baseline: 1.1170x; 1.0522x over previous
//
#include <hip/hip_runtime.h>

typedef unsigned short ushort_t;
typedef unsigned int uint_t;
typedef _Float16 f16;
typedef __attribute__((ext_vector_type(8))) _Float16 f16x8;
typedef __attribute__((ext_vector_type(8))) unsigned short u16x8;
typedef __attribute__((ext_vector_type(4))) float f32x4;

#define IMG_S 264
#define IMG_H 262
#define PLANE (IMG_H * IMG_S)   // 69168 elements per padded plane
#define NPLANES 61              // 30 x-planes, 30 ups-planes, 1 zero plane
#define KTOT 1472               // 1470 padded to 46*32
#define KREAL 1470
#define NHID 2048
#define NPIX 65536
#define BM 256
#define BN 128
#define BK 32
#define KSTEPS (KTOT / BK)      // 46
#define SA 8.0f                 // A pre-scale (avoid fp16 denorm lo)
#define SB 512.0f               // W1 pre-scale
#define INV_S (1.0f / (SA * SB))  // exact power of two

__device__ __forceinline__ uint_t f16pair(float f) {
    // pack fp16(f) | fp16(f - fp16(f)) << 16  (hi in low bits)
    f16 h = (f16)f;
    f16 l = (f16)(f - (float)h);
    union { f16 a; ushort_t b; } uh, ul;
    uh.a = h; ul.a = l;
    return (uint_t)uh.b | ((uint_t)ul.b << 16);
}

// ---------------------------------------------------------------- pad images
__global__ void pad_imgs(const float* __restrict__ x, const float* __restrict__ xu,
                         uint_t* __restrict__ img2) {
    int idx = blockIdx.x * 256 + threadIdx.x;
    if (idx >= NPLANES * PLANE) return;
    int plane = idx / PLANE;
    int e = idx - plane * PLANE;
    int i = e / IMG_S;
    int j = e - i * IMG_S;
    uint_t v = 0;
    if (plane < 60 && i >= 3 && i < 259 && j >= 3 && j < 259) {
        const float* src = (plane < 30) ? x : xu;
        int c = (plane < 30) ? plane : plane - 30;
        float f = SA * src[(size_t)c * 65536 + (size_t)(i - 3) * 256 + (j - 3)];
        v = f16pair(f);
    }
    img2[idx] = v;
}

// ---------------------------------------------------------------- boff table
__global__ void boff_kernel(int* __restrict__ boff) {
    int f = blockIdx.x * 256 + threadIdx.x;
    if (f >= KTOT) return;
    int off;
    if (f < 720) {                    // causal from x: c=f/24, p=f%24
        int c = f / 24, p = f - c * 24;
        off = c * PLANE + (p / 7) * IMG_S + (p % 7);
    } else if (f < KREAL) {           // ups slice [720:): c=f/49, p=f%49
        int c = f / 49, p = f - c * 49;
        off = (30 + c) * PLANE + (p / 7) * IMG_S + (p % 7);
    } else {
        off = 60 * PLANE;             // zero plane (K padding)
    }
    boff[f] = off;
}

// ------------------------------------- W1 -> W1T hi/lo (fp16, scaled, K-padded)
__global__ void w1t_kernel(const float* __restrict__ w1,
                           ushort_t* __restrict__ w1t_hi, ushort_t* __restrict__ w1t_lo) {
    __shared__ float tile[32][33];
    const int bk  = blockIdx.x % 46;
    const int bnh = blockIdx.x / 46;
    const int t = threadIdx.x;
    const int r = t >> 5, c = t & 31;
#pragma unroll
    for (int s = 0; s < 4; ++s) {
        int kk = bk * 32 + s * 8 + r;
        int nh = bnh * 32 + c;
        tile[s * 8 + r][c] = (kk < KREAL) ? SB * w1[(size_t)kk * NHID + nh] : 0.0f;
    }
    __syncthreads();
#pragma unroll
    for (int s = 0; s < 4; ++s) {
        int nh = bnh * 32 + s * 8 + r;
        int kk = bk * 32 + c;
        float v = tile[c][s * 8 + r];
        uint_t p = f16pair(v);
        w1t_hi[(size_t)nh * KTOT + kk] = (ushort_t)(p & 0xffffu);
        w1t_lo[(size_t)nh * KTOT + kk] = (ushort_t)(p >> 16);
    }
}

// ------------------------------------------------------------- fused GEMM
// split-fp16 GEMM1, BM=256 x BN=128, BK=32; 256 threads, 2x2 waves of 128x64.
// Depth-1 register prefetch: next tile's global loads issue before this
// tile's MFMAs; vmcnt waits land in the next store phase (T14 pattern).
__global__ __launch_bounds__(256, 2)
void fused_gemm(const uint_t* __restrict__ img2,
                const ushort_t* __restrict__ w1t_hi,
                const ushort_t* __restrict__ w1t_lo,
                const int* __restrict__ boff,
                const float* __restrict__ b1,
                const float* __restrict__ w2,
                float* __restrict__ accum) {
    __shared__ ushort_t Ah[BM * BK];   // 16 KB
    __shared__ ushort_t Al[BM * BK];   // 16 KB
    __shared__ ushort_t Bh[BN * BK];   // 8 KB
    __shared__ ushort_t Bl[BN * BK];   // 8 KB   (total 48 KB)

    const int tid  = threadIdx.x;
    const int bid  = blockIdx.x;
    const int brow = bid >> 4;          // 256 row-blocks (image row h = brow)
    const int bcol = bid & 15;          // 16 col-blocks
    const int lane = tid & 63;
    const int wid  = tid >> 6;
    const int wm = wid >> 1;            // 0..1 -> 128-row half
    const int wn = wid & 1;             // 0..1 -> 64-col half

    // A staging: thread = row (pixel w = tid on image row h = brow), all 32 k
    const int hwoff = brow * IMG_S + tid;
    int aaddr[4];
#pragma unroll
    for (int s = 0; s < 4; ++s)
        aaddr[s] = (tid * (BK * 2) + s * 16) ^ ((tid & 7) << 4);
    // B staging: thread -> n-row tid>>1, k-half (tid&1)*16
    const int bn_ = tid >> 1;
    const int kh  = (tid & 1) * 16;
    int baddr[2];
#pragma unroll
    for (int s = 0; s < 2; ++s)
        baddr[s] = (bn_ * (BK * 2) + kh * 2 + s * 16) ^ ((bn_ & 7) << 4);
    const size_t bglob = (size_t)(bcol * BN + bn_) * KTOT + kh;

    // ---- prefetch registers (tile kt=0)
    uint_t aw[4][8];
    u16x8 bwh[2], bwl[2];
#pragma unroll
    for (int s = 0; s < 4; ++s)
#pragma unroll
        for (int i = 0; i < 8; ++i)
            aw[s][i] = img2[boff[s * 8 + i] + hwoff];
#pragma unroll
    for (int s = 0; s < 2; ++s) {
        bwh[s] = *reinterpret_cast<const u16x8*>(w1t_hi + bglob + s * 8);
        bwl[s] = *reinterpret_cast<const u16x8*>(w1t_lo + bglob + s * 8);
    }

    f32x4 zero = {0.f, 0.f, 0.f, 0.f};
    f32x4 acc[8][4];
#pragma unroll
    for (int mi = 0; mi < 8; ++mi)
#pragma unroll
        for (int ni = 0; ni < 4; ++ni) acc[mi][ni] = zero;

    for (int kt = 0; kt < KSTEPS; ++kt) {
        __syncthreads();
        // ---- store phase: prefetched regs -> LDS
#pragma unroll
        for (int s = 0; s < 2; ++s) {
            *reinterpret_cast<u16x8*>((char*)Bh + baddr[s]) = bwh[s];
            *reinterpret_cast<u16x8*>((char*)Bl + baddr[s]) = bwl[s];
        }
#pragma unroll
        for (int s = 0; s < 4; ++s) {
            u16x8 hi, lo;
            uint_t* hp = reinterpret_cast<uint_t*>(&hi);
            uint_t* lp = reinterpret_cast<uint_t*>(&lo);
#pragma unroll
            for (int i = 0; i < 4; ++i) {
                hp[i] = __builtin_amdgcn_perm(aw[s][2 * i + 1], aw[s][2 * i], 0x05040100u);
                lp[i] = __builtin_amdgcn_perm(aw[s][2 * i + 1], aw[s][2 * i], 0x07060302u);
            }
            *reinterpret_cast<u16x8*>((char*)Ah + aaddr[s]) = hi;
            *reinterpret_cast<u16x8*>((char*)Al + aaddr[s]) = lo;
        }
        __syncthreads();
        // ---- issue next tile's global loads (hide under MFMAs below)
        if (kt + 1 < KSTEPS) {
            const int f0n = (kt + 1) * BK;
#pragma unroll
            for (int s = 0; s < 4; ++s)
#pragma unroll
                for (int i = 0; i < 8; ++i)
                    aw[s][i] = img2[boff[f0n + s * 8 + i] + hwoff];
            const size_t bsrc = bglob + (size_t)(kt + 1) * BK;
#pragma unroll
            for (int s = 0; s < 2; ++s) {
                bwh[s] = *reinterpret_cast<const u16x8*>(w1t_hi + bsrc + s * 8);
                bwl[s] = *reinterpret_cast<const u16x8*>(w1t_lo + bsrc + s * 8);
            }
        }
        // ---- fragments + 96 MFMA per wave (hi*hi, hi*lo, lo*hi)
        f16x8 bfh[4], bfl[4];
#pragma unroll
        for (int ni = 0; ni < 4; ++ni) {
            int n = wn * 64 + ni * 16 + (lane & 15);
            int bb = (n * (BK * 2) + (lane >> 4) * 16) ^ ((n & 7) << 4);
            bfh[ni] = *reinterpret_cast<const f16x8*>((char*)Bh + bb);
            bfl[ni] = *reinterpret_cast<const f16x8*>((char*)Bl + bb);
        }
#pragma unroll
        for (int mi = 0; mi < 8; ++mi) {
            int m = wm * 128 + mi * 16 + (lane & 15);
            int ab = (m * (BK * 2) + (lane >> 4) * 16) ^ ((m & 7) << 4);
            f16x8 afh = *reinterpret_cast<const f16x8*>((char*)Ah + ab);
            f16x8 afl = *reinterpret_cast<const f16x8*>((char*)Al + ab);
#pragma unroll
            for (int ni = 0; ni < 4; ++ni) {
                acc[mi][ni] = __builtin_amdgcn_mfma_f32_16x16x32_f16(
                    afh, bfh[ni], acc[mi][ni], 0, 0, 0);
                acc[mi][ni] = __builtin_amdgcn_mfma_f32_16x16x32_f16(
                    afh, bfl[ni], acc[mi][ni], 0, 0, 0);
                acc[mi][ni] = __builtin_amdgcn_mfma_f32_16x16x32_f16(
                    afl, bfh[ni], acc[mi][ni], 0, 0, 0);
            }
        }
    }

    // epilogue: h = relu(acc/4096 + b1); partial out = h @ W2; atomic accumulate
    const int pix0 = brow * BM;
    float b1v[4], w2v[4][6];
#pragma unroll
    for (int ni = 0; ni < 4; ++ni) {
        int n = bcol * BN + wn * 64 + ni * 16 + (lane & 15);
        b1v[ni] = b1[n];
#pragma unroll
        for (int o = 0; o < 6; ++o) w2v[ni][o] = w2[n * 6 + o];
    }
#pragma unroll
    for (int mi = 0; mi < 8; ++mi) {
        float p[4][6];
#pragma unroll
        for (int r = 0; r < 4; ++r)
#pragma unroll
            for (int o = 0; o < 6; ++o) p[r][o] = 0.f;
#pragma unroll
        for (int ni = 0; ni < 4; ++ni) {
#pragma unroll
            for (int r = 0; r < 4; ++r) {
                float hv = fmaxf(acc[mi][ni][r] * INV_S + b1v[ni], 0.0f);
#pragma unroll
                for (int o = 0; o < 6; ++o) p[r][o] += hv * w2v[ni][o];
            }
        }
#pragma unroll
        for (int r = 0; r < 4; ++r) {
#pragma unroll
            for (int o = 0; o < 6; ++o) {
                float v = p[r][o];
                v += __shfl_xor(v, 1, 16);
                v += __shfl_xor(v, 2, 16);
                v += __shfl_xor(v, 4, 16);
                v += __shfl_xor(v, 8, 16);
                int q = r * 6 + o;
                if ((lane & 15) == (q & 15)) {
                    int orow = wm * 128 + mi * 16 + (lane >> 4) * 4 + r;
                    atomicAdd(&accum[(size_t)(pix0 + orow) * 6 + o], v);
                }
            }
        }
    }
}

// ------------------------------------------------------------- final transform
__global__ void transform_k(const float* __restrict__ accum, const float* __restrict__ b2,
                            float* __restrict__ out) {
    int n = blockIdx.x * 256 + threadIdx.x;
    if (n >= NPIX) return;
#pragma unroll
    for (int ch = 0; ch < 3; ++ch) {
        float m = accum[(size_t)n * 6 + ch * 2 + 0] + b2[ch * 2 + 0];
        float s = accum[(size_t)n * 6 + ch * 2 + 1] + b2[ch * 2 + 1];
        out[(size_t)n * 6 + ch * 2 + 0] = m * 255.0f;
        float denom = 1.0f - s + 0.1f;
        float sc = s / denom * 100.0f;
        sc = fminf(fmaxf(sc, 1e-8f), 1000.0f);
        out[(size_t)n * 6 + ch * 2 + 1] = sc;
    }
}

// ---------------------------------------------------------------- launch
extern "C" void kernel_launch(void* const* d_in, const int* in_sizes, int n_in,
                              void* d_out, int out_size, void* d_ws, size_t ws_size,
                              hipStream_t stream) {
    const float* x  = (const float*)d_in[0];
    const float* xu = (const float*)d_in[1];
    const float* W1 = (const float*)d_in[2];
    const float* b1 = (const float*)d_in[3];
    const float* W2 = (const float*)d_in[4];
    const float* b2 = (const float*)d_in[5];
    float* out = (float*)d_out;
    char* ws = (char*)d_ws;

    // workspace layout (~30.5 MiB)
    const size_t OFF_W1H  = 16877056;                       // img2: 61*69168*4 B
    const size_t OFF_W1L  = OFF_W1H + (size_t)NHID * KTOT * 2;
    const size_t OFF_ACC  = OFF_W1L + (size_t)NHID * KTOT * 2;
    const size_t OFF_BOFF = OFF_ACC + (size_t)NPIX * 6 * sizeof(float);
    uint_t* img2    = (uint_t*)ws;
    ushort_t* w1t_h = (ushort_t*)(ws + OFF_W1H);
    ushort_t* w1t_l = (ushort_t*)(ws + OFF_W1L);
    float* accum    = (float*)(ws + OFF_ACC);
    int* boff       = (int*)(ws + OFF_BOFF);
    (void)ws_size; (void)in_sizes; (void)n_in; (void)out_size;

    hipMemsetAsync(accum, 0, (size_t)NPIX * 6 * sizeof(float), stream);

    int padN = NPLANES * PLANE;
    pad_imgs<<<(padN + 255) / 256, 256, 0, stream>>>(x, xu, img2);
    boff_kernel<<<(KTOT + 255) / 256, 256, 0, stream>>>(boff);
    w1t_kernel<<<46 * 64, 256, 0, stream>>>(W1, w1t_h, w1t_l);
    fused_gemm<<<256 * 16, 256, 0, stream>>>(img2, w1t_h, w1t_l, boff, b1, W2, accum);
    transform_k<<<NPIX / 256, 256, 0, stream>>>(accum, b2, out);
}

// Round 11
// 1336.829 us; speedup vs baseline: 1.1926x; 1.0677x over previous
//
#include <hip/hip_runtime.h>

typedef unsigned short ushort_t;
typedef unsigned int uint_t;
typedef _Float16 f16;
typedef __attribute__((ext_vector_type(8))) _Float16 f16x8;
typedef __attribute__((ext_vector_type(8))) unsigned short u16x8;
typedef __attribute__((ext_vector_type(4))) float f32x4;

#define IMG_S 264
#define IMG_H 262
#define PLANE (IMG_H * IMG_S)   // 69168 elements per padded plane
#define NPLANES 61              // 30 x-planes, 30 ups-planes, 1 zero plane
#define KTOT 1472               // 1470 padded to 46*32
#define KREAL 1470
#define NHID 2048
#define NPIX 65536
#define BM 256
#define BN 128
#define BK 32
#define KSTEPS (KTOT / BK)      // 46
#define SA 8.0f                 // A pre-scale (avoid fp16 denorm lo)
#define SB 512.0f               // W1 pre-scale
#define INV_S (1.0f / (SA * SB))  // exact power of two

__device__ __forceinline__ uint_t f16pair(float f) {
    // pack fp16(f) | fp16(f - fp16(f)) << 16  (hi in low bits)
    f16 h = (f16)f;
    f16 l = (f16)(f - (float)h);
    union { f16 a; ushort_t b; } uh, ul;
    uh.a = h; ul.a = l;
    return (uint_t)uh.b | ((uint_t)ul.b << 16);
}

// ---------------------------------------------------------------- pad images
__global__ void pad_imgs(const float* __restrict__ x, const float* __restrict__ xu,
                         uint_t* __restrict__ img2) {
    int idx = blockIdx.x * 256 + threadIdx.x;
    if (idx >= NPLANES * PLANE) return;
    int plane = idx / PLANE;
    int e = idx - plane * PLANE;
    int i = e / IMG_S;
    int j = e - i * IMG_S;
    uint_t v = 0;
    if (plane < 60 && i >= 3 && i < 259 && j >= 3 && j < 259) {
        const float* src = (plane < 30) ? x : xu;
        int c = (plane < 30) ? plane : plane - 30;
        float f = SA * src[(size_t)c * 65536 + (size_t)(i - 3) * 256 + (j - 3)];
        v = f16pair(f);
    }
    img2[idx] = v;
}

// ------------------------------------------------- boffB table (BYTE offsets)
__global__ void boff_kernel(int* __restrict__ boffB) {
    int f = blockIdx.x * 256 + threadIdx.x;
    if (f >= KTOT) return;
    int off;
    if (f < 720) {                    // causal from x: c=f/24, p=f%24
        int c = f / 24, p = f - c * 24;
        off = c * PLANE + (p / 7) * IMG_S + (p % 7);
    } else if (f < KREAL) {           // ups slice [720:): c=f/49, p=f%49
        int c = f / 49, p = f - c * 49;
        off = (30 + c) * PLANE + (p / 7) * IMG_S + (p % 7);
    } else {
        off = 60 * PLANE;             // zero plane (K padding)
    }
    boffB[f] = off * 4;               // byte offset into img2
}

// ------------------------------------- W1 -> W1T hi/lo (fp16, scaled, K-padded)
__global__ void w1t_kernel(const float* __restrict__ w1,
                           ushort_t* __restrict__ w1t_hi, ushort_t* __restrict__ w1t_lo) {
    __shared__ float tile[32][33];
    const int bk  = blockIdx.x % 46;
    const int bnh = blockIdx.x / 46;
    const int t = threadIdx.x;
    const int r = t >> 5, c = t & 31;
#pragma unroll
    for (int s = 0; s < 4; ++s) {
        int kk = bk * 32 + s * 8 + r;
        int nh = bnh * 32 + c;
        tile[s * 8 + r][c] = (kk < KREAL) ? SB * w1[(size_t)kk * NHID + nh] : 0.0f;
    }
    __syncthreads();
#pragma unroll
    for (int s = 0; s < 4; ++s) {
        int nh = bnh * 32 + s * 8 + r;
        int kk = bk * 32 + c;
        float v = tile[c][s * 8 + r];
        uint_t p = f16pair(v);
        w1t_hi[(size_t)nh * KTOT + kk] = (ushort_t)(p & 0xffffu);
        w1t_lo[(size_t)nh * KTOT + kk] = (ushort_t)(p >> 16);
    }
}

// ------------------------------------------------------------- fused GEMM
// split-fp16 GEMM1, BM=256 x BN=128, BK=32; 256 threads, 2x2 waves of 128x64.
// Depth-1 register prefetch (T14) + scalar-base gather addressing +
// pipelined A-fragment reads + setprio around MFMA clusters (T5).
__global__ __launch_bounds__(256, 2)
void fused_gemm(const uint_t* __restrict__ img2,
                const ushort_t* __restrict__ w1t_hi,
                const ushort_t* __restrict__ w1t_lo,
                const int* __restrict__ boffB,
                const float* __restrict__ b1,
                const float* __restrict__ w2,
                float* __restrict__ accum) {
    __shared__ ushort_t Ah[BM * BK];   // 16 KB
    __shared__ ushort_t Al[BM * BK];   // 16 KB
    __shared__ ushort_t Bh[BN * BK];   // 8 KB
    __shared__ ushort_t Bl[BN * BK];   // 8 KB   (total 48 KB)

    const int tid  = threadIdx.x;
    const int bid  = blockIdx.x;
    const int brow = bid >> 4;          // 256 row-blocks (image row h = brow)
    const int bcol = bid & 15;          // 16 col-blocks
    const int lane = tid & 63;
    const int wid  = tid >> 6;
    const int wm = wid >> 1;            // 0..1 -> 128-row half
    const int wn = wid & 1;             // 0..1 -> 64-col half

    // A staging: thread = row (pixel w = tid on image row h = brow), all 32 k.
    // Gather uses uniform (scalar) boffB byte offsets + thread-varying element
    // index -> saddr+voffset form, no per-load 64-bit VALU chains.
    const int hw = brow * IMG_S + tid;  // element index into each plane
    int aaddr[4];
#pragma unroll
    for (int s = 0; s < 4; ++s)
        aaddr[s] = (tid * (BK * 2) + s * 16) ^ ((tid & 7) << 4);
    // B staging: thread -> n-row tid>>1, k-half (tid&1)*16
    const int bn_ = tid >> 1;
    const int kh  = (tid & 1) * 16;
    int baddr[2];
#pragma unroll
    for (int s = 0; s < 2; ++s)
        baddr[s] = (bn_ * (BK * 2) + kh * 2 + s * 16) ^ ((bn_ & 7) << 4);
    const size_t bglob = (size_t)(bcol * BN + bn_) * KTOT + kh;

    // ---- prefetch registers (tile kt=0)
    uint_t aw[4][8];
    u16x8 bwh[2], bwl[2];
#pragma unroll
    for (int s = 0; s < 4; ++s)
#pragma unroll
        for (int i = 0; i < 8; ++i) {
            const uint_t* p = (const uint_t*)((const char*)img2 + boffB[s * 8 + i]);
            aw[s][i] = p[hw];
        }
#pragma unroll
    for (int s = 0; s < 2; ++s) {
        bwh[s] = *reinterpret_cast<const u16x8*>(w1t_hi + bglob + s * 8);
        bwl[s] = *reinterpret_cast<const u16x8*>(w1t_lo + bglob + s * 8);
    }

    f32x4 zero = {0.f, 0.f, 0.f, 0.f};
    f32x4 acc[8][4];
#pragma unroll
    for (int mi = 0; mi < 8; ++mi)
#pragma unroll
        for (int ni = 0; ni < 4; ++ni) acc[mi][ni] = zero;

    for (int kt = 0; kt < KSTEPS; ++kt) {
        __syncthreads();
        // ---- store phase: prefetched regs -> LDS
#pragma unroll
        for (int s = 0; s < 2; ++s) {
            *reinterpret_cast<u16x8*>((char*)Bh + baddr[s]) = bwh[s];
            *reinterpret_cast<u16x8*>((char*)Bl + baddr[s]) = bwl[s];
        }
#pragma unroll
        for (int s = 0; s < 4; ++s) {
            u16x8 hi, lo;
            uint_t* hp = reinterpret_cast<uint_t*>(&hi);
            uint_t* lp = reinterpret_cast<uint_t*>(&lo);
#pragma unroll
            for (int i = 0; i < 4; ++i) {
                hp[i] = __builtin_amdgcn_perm(aw[s][2 * i + 1], aw[s][2 * i], 0x05040100u);
                lp[i] = __builtin_amdgcn_perm(aw[s][2 * i + 1], aw[s][2 * i], 0x07060302u);
            }
            *reinterpret_cast<u16x8*>((char*)Ah + aaddr[s]) = hi;
            *reinterpret_cast<u16x8*>((char*)Al + aaddr[s]) = lo;
        }
        __syncthreads();
        // ---- issue next tile's global loads (hide under MFMAs below)
        if (kt + 1 < KSTEPS) {
            const int f0n = (kt + 1) * BK;
#pragma unroll
            for (int s = 0; s < 4; ++s)
#pragma unroll
                for (int i = 0; i < 8; ++i) {
                    const uint_t* p =
                        (const uint_t*)((const char*)img2 + boffB[f0n + s * 8 + i]);
                    aw[s][i] = p[hw];
                }
            const size_t bsrc = bglob + (size_t)(kt + 1) * BK;
#pragma unroll
            for (int s = 0; s < 2; ++s) {
                bwh[s] = *reinterpret_cast<const u16x8*>(w1t_hi + bsrc + s * 8);
                bwl[s] = *reinterpret_cast<const u16x8*>(w1t_lo + bsrc + s * 8);
            }
        }
        // ---- B fragments, then pipelined A-fragment loop with MFMA clusters
        f16x8 bfh[4], bfl[4];
#pragma unroll
        for (int ni = 0; ni < 4; ++ni) {
            int n = wn * 64 + ni * 16 + (lane & 15);
            int bb = (n * (BK * 2) + (lane >> 4) * 16) ^ ((n & 7) << 4);
            bfh[ni] = *reinterpret_cast<const f16x8*>((char*)Bh + bb);
            bfl[ni] = *reinterpret_cast<const f16x8*>((char*)Bl + bb);
        }
        const int mbase = wm * 128 + (lane & 15);
        const int koff  = (lane >> 4) * 16;
        int ab0 = (mbase * (BK * 2) + koff) ^ ((mbase & 7) << 4);
        f16x8 afh = *reinterpret_cast<const f16x8*>((char*)Ah + ab0);
        f16x8 afl = *reinterpret_cast<const f16x8*>((char*)Al + ab0);
#pragma unroll
        for (int mi = 0; mi < 8; ++mi) {
            f16x8 nfh, nfl;
            if (mi < 7) {               // load next fragment before this cluster
                int m = mbase + (mi + 1) * 16;
                int ab = (m * (BK * 2) + koff) ^ ((m & 7) << 4);
                nfh = *reinterpret_cast<const f16x8*>((char*)Ah + ab);
                nfl = *reinterpret_cast<const f16x8*>((char*)Al + ab);
            }
            __builtin_amdgcn_s_setprio(1);
#pragma unroll
            for (int ni = 0; ni < 4; ++ni) {
                acc[mi][ni] = __builtin_amdgcn_mfma_f32_16x16x32_f16(
                    afh, bfh[ni], acc[mi][ni], 0, 0, 0);
                acc[mi][ni] = __builtin_amdgcn_mfma_f32_16x16x32_f16(
                    afh, bfl[ni], acc[mi][ni], 0, 0, 0);
                acc[mi][ni] = __builtin_amdgcn_mfma_f32_16x16x32_f16(
                    afl, bfh[ni], acc[mi][ni], 0, 0, 0);
            }
            __builtin_amdgcn_s_setprio(0);
            afh = nfh; afl = nfl;
        }
    }

    // epilogue: h = relu(acc/4096 + b1); partial out = h @ W2; atomic accumulate
    const int pix0 = brow * BM;
    float b1v[4], w2v[4][6];
#pragma unroll
    for (int ni = 0; ni < 4; ++ni) {
        int n = bcol * BN + wn * 64 + ni * 16 + (lane & 15);
        b1v[ni] = b1[n];
#pragma unroll
        for (int o = 0; o < 6; ++o) w2v[ni][o] = w2[n * 6 + o];
    }
#pragma unroll
    for (int mi = 0; mi < 8; ++mi) {
        float p[4][6];
#pragma unroll
        for (int r = 0; r < 4; ++r)
#pragma unroll
            for (int o = 0; o < 6; ++o) p[r][o] = 0.f;
#pragma unroll
        for (int ni = 0; ni < 4; ++ni) {
#pragma unroll
            for (int r = 0; r < 4; ++r) {
                float hv = fmaxf(acc[mi][ni][r] * INV_S + b1v[ni], 0.0f);
#pragma unroll
                for (int o = 0; o < 6; ++o) p[r][o] += hv * w2v[ni][o];
            }
        }
#pragma unroll
        for (int r = 0; r < 4; ++r) {
#pragma unroll
            for (int o = 0; o < 6; ++o) {
                float v = p[r][o];
                v += __shfl_xor(v, 1, 16);
                v += __shfl_xor(v, 2, 16);
                v += __shfl_xor(v, 4, 16);
                v += __shfl_xor(v, 8, 16);
                int q = r * 6 + o;
                if ((lane & 15) == (q & 15)) {
                    int orow = wm * 128 + mi * 16 + (lane >> 4) * 4 + r;
                    atomicAdd(&accum[(size_t)(pix0 + orow) * 6 + o], v);
                }
            }
        }
    }
}

// ------------------------------------------------------------- final transform
__global__ void transform_k(const float* __restrict__ accum, const float* __restrict__ b2,
                            float* __restrict__ out) {
    int n = blockIdx.x * 256 + threadIdx.x;
    if (n >= NPIX) return;
#pragma unroll
    for (int ch = 0; ch < 3; ++ch) {
        float m = accum[(size_t)n * 6 + ch * 2 + 0] + b2[ch * 2 + 0];
        float s = accum[(size_t)n * 6 + ch * 2 + 1] + b2[ch * 2 + 1];
        out[(size_t)n * 6 + ch * 2 + 0] = m * 255.0f;
        float denom = 1.0f - s + 0.1f;
        float sc = s / denom * 100.0f;
        sc = fminf(fmaxf(sc, 1e-8f), 1000.0f);
        out[(size_t)n * 6 + ch * 2 + 1] = sc;
    }
}

// ---------------------------------------------------------------- launch
extern "C" void kernel_launch(void* const* d_in, const int* in_sizes, int n_in,
                              void* d_out, int out_size, void* d_ws, size_t ws_size,
                              hipStream_t stream) {
    const float* x  = (const float*)d_in[0];
    const float* xu = (const float*)d_in[1];
    const float* W1 = (const float*)d_in[2];
    const float* b1 = (const float*)d_in[3];
    const float* W2 = (const float*)d_in[4];
    const float* b2 = (const float*)d_in[5];
    float* out = (float*)d_out;
    char* ws = (char*)d_ws;

    // workspace layout (~30.5 MiB)
    const size_t OFF_W1H  = 16877056;                       // img2: 61*69168*4 B
    const size_t OFF_W1L  = OFF_W1H + (size_t)NHID * KTOT * 2;
    const size_t OFF_ACC  = OFF_W1L + (size_t)NHID * KTOT * 2;
    const size_t OFF_BOFF = OFF_ACC + (size_t)NPIX * 6 * sizeof(float);
    uint_t* img2    = (uint_t*)ws;
    ushort_t* w1t_h = (ushort_t*)(ws + OFF_W1H);
    ushort_t* w1t_l = (ushort_t*)(ws + OFF_W1L);
    float* accum    = (float*)(ws + OFF_ACC);
    int* boffB      = (int*)(ws + OFF_BOFF);
    (void)ws_size; (void)in_sizes; (void)n_in; (void)out_size;

    hipMemsetAsync(accum, 0, (size_t)NPIX * 6 * sizeof(float), stream);

    int padN = NPLANES * PLANE;
    pad_imgs<<<(padN + 255) / 256, 256, 0, stream>>>(x, xu, img2);
    boff_kernel<<<(KTOT + 255) / 256, 256, 0, stream>>>(boffB);
    w1t_kernel<<<46 * 64, 256, 0, stream>>>(W1, w1t_h, w1t_l);
    fused_gemm<<<256 * 16, 256, 0, stream>>>(img2, w1t_h, w1t_l, boffB, b1, W2, accum);
    transform_k<<<NPIX / 256, 256, 0, stream>>>(accum, b2, out);
}